// Round 6
// baseline (264.469 us; speedup 1.0000x reference)
//
#include <hip/hip_runtime.h>
#include <stdint.h>

#define EMPTY 0xFFFFFFFFu
#define HSZ 1024

// In-wave phase sync: waits this wave's LDS ops; no block barrier needed.
#define WSYNC() asm volatile("s_waitcnt lgkmcnt(0)" ::: "memory")

__device__ __forceinline__ uint32_t f2s(float f) {
    uint32_t u = __float_as_uint(f);
    return (u & 0x80000000u) ? ~u : (u | 0x80000000u);
}
__device__ __forceinline__ float s2f(uint32_t s) {
    uint32_t u = (s & 0x80000000u) ? (s & 0x7fffffffu) : ~s;
    return __uint_as_float(u);
}

// One block per (image,chunk); wave c (c=tid>>6) owns diagram c: 0=-y,1=+y,2=-x,3=+x.
// All per-case phases are intra-wave (WSYNC only); 2 block barriers total.
__global__ __launch_bounds__(256) void toploss_one(
        const float* __restrict__ xin, const float* __restrict__ yin,
        const int* __restrict__ offs, float* __restrict__ ws,
        float* __restrict__ out)
{
    __shared__ uint32_t key[4][1024];             // case-signed sort keys
    __shared__ unsigned short sd[4][1024];        // steepest-descent -> basin min
    __shared__ unsigned short rnk[4][1024];       // basin min vertex -> dense rank
    __shared__ uint32_t minkey[4][384];           // rank -> basin min key
    __shared__ uint32_t hpair[4][HSZ];            // pair-dedup hash
    __shared__ uint32_t hwt[4][HSZ];              // pair min weight
    __shared__ unsigned long long elist[4][1024]; // sorted saddle edges
    __shared__ uint32_t poslist[2][256];          // positive bars of x-cases
    __shared__ int cnts[4], ecnts[4], npos4[4];
    __shared__ float tot2[2], psum[2];

    const int q = blockIdx.x;                     // b*2 + chunk
    const int b = q >> 1;
    const int tid = threadIdx.x;
    const int c = tid >> 6;
    const int lane = tid & 63;
    const int off0 = offs[q * 2 + 0], off1 = offs[q * 2 + 1];
    const float* img = (c >> 1) ? (xin + b * 160000) : (yin + b * 160000);
    const bool neg = ((c & 1) == 0);

    if (lane == 0) { cnts[c] = 0; ecnts[c] = 0; }
    if (c >= 2) for (int s = lane; s < 256; s += 64) poslist[c - 2][s] = 0u;
    for (int s = lane; s < HSZ; s += 64) { hpair[c][s] = EMPTY; hwt[c][s] = EMPTY; }

    // ---- load chunk with +1.0 contour border; f2s(-v) == ~f2s(v) ----
    uint32_t mk[16];
    #pragma unroll
    for (int s = 0; s < 16; ++s) {
        int u = s * 64 + lane;
        int i = u >> 5, j = u & 31;
        bool border = (i == 0) | (i == 31) | (j == 0) | (j == 31);
        float val = border ? 1.0f : img[(off0 + i - 1) * 400 + (off1 + j - 1)];
        uint32_t k = f2s(val);
        k = neg ? ~k : k;
        mk[s] = k;
        key[c][u] = k;
    }
    WSYNC();

    // ---- steepest descent (strict total order (key,idx)) ----
    const int DI[6] = {-1, 1, 0, 0, 1, -1};
    const int DJ[6] = { 0, 0,-1, 1, 1, -1};
    #pragma unroll
    for (int s = 0; s < 16; ++s) {
        int u = s * 64 + lane;
        int i = u >> 5, j = u & 31;
        unsigned long long best = ((unsigned long long)mk[s] << 10) | (unsigned)u;
        int bi = u;
        #pragma unroll
        for (int d = 0; d < 6; ++d) {
            int ni = i + DI[d], nj = j + DJ[d];
            if (ni < 0 || ni > 31 || nj < 0 || nj > 31) continue;
            int nb = (ni << 5) | nj;
            unsigned long long kn = ((unsigned long long)key[c][nb] << 10) | (unsigned)nb;
            if (kn < best) { best = kn; bi = nb; }
        }
        sd[c][u] = (unsigned short)bi;
    }
    WSYNC();

    // ---- pointer jumping to basin min (monotone; early-out via ballot) ----
    for (int r = 0; r < 10; ++r) {
        bool ch = false;
        #pragma unroll
        for (int s = 0; s < 16; ++s) {
            int u = s * 64 + lane;
            int a = sd[c][u], a2 = sd[c][a];
            if (a2 != a) { sd[c][u] = (unsigned short)a2; ch = true; }
        }
        WSYNC();
        if (__ballot(ch) == 0ull) break;
    }

    // ---- dense-rank minima ----
    #pragma unroll
    for (int s = 0; s < 16; ++s) {
        int u = s * 64 + lane;
        if (sd[c][u] == (unsigned short)u) {
            int r = atomicAdd(&cnts[c], 1);
            rnk[c][u] = (unsigned short)r;
            if (r < 384) minkey[c][r] = mk[s];
        }
    }
    WSYNC();

    // ---- cross-basin edges, per-pair min weight via hash ----
    const int CDI[3] = {1, 0, 1}, CDJ[3] = {0, 1, 1};
    #pragma unroll
    for (int s = 0; s < 16; ++s) {
        int u = s * 64 + lane;
        int i = u >> 5, j = u & 31;
        uint32_t ku = mk[s];
        int sa = sd[c][u];
        #pragma unroll
        for (int d = 0; d < 3; ++d) {
            int ni = i + CDI[d], nj = j + CDJ[d];
            if (ni > 31 || nj > 31) continue;
            int nb = (ni << 5) | nj;
            int sb = sd[c][nb];
            if (sa == sb) continue;
            uint32_t kn = key[c][nb];
            uint32_t w = ku > kn ? ku : kn;
            int a = rnk[c][sa], bb = rnk[c][sb];
            if (a > bb) { int t = a; a = bb; bb = t; }
            uint32_t pk = ((uint32_t)a << 9) | (uint32_t)bb;
            uint32_t h = (pk * 2654435761u) >> 22;
            while (true) {
                uint32_t old = atomicCAS(&hpair[c][h], EMPTY, pk);
                if (old == EMPTY || old == pk) { atomicMin(&hwt[c][h], w); break; }
                h = (h + 1) & (HSZ - 1);
            }
        }
    }
    WSYNC();

    // ---- compact hash -> edge list ----
    for (int s = lane; s < HSZ; s += 64) {
        uint32_t pk = hpair[c][s];
        if (pk != EMPTY) {
            int e = atomicAdd(&ecnts[c], 1);
            elist[c][e] = ((unsigned long long)hwt[c][s] << 18) | pk;
        }
    }
    WSYNC();
    const int m = ecnts[c];                       // planar: <= 3*nb-6 <= 1017
    const int msort = (m <= 512) ? 512 : 1024;
    for (int s2 = m + lane; s2 < msort; s2 += 64) elist[c][s2] = ~0ull;
    WSYNC();

    // ---- in-wave bitonic sort ascending by (weight, pair) ----
    for (int k = 2; k <= msort; k <<= 1) {
        for (int jj = k >> 1; jj > 0; jj >>= 1) {
            for (int i2 = lane; i2 < msort; i2 += 64) {
                int l = i2 ^ jj;
                if (l > i2) {
                    unsigned long long A = elist[c][i2], B = elist[c][l];
                    bool up = ((i2 & k) == 0);
                    if ((A > B) == up) { elist[c][i2] = B; elist[c][l] = A; }
                }
            }
            WSYNC();
        }
    }

    // ---- elder-rule Kruskal, union-find in this wave's registers ----
    unsigned long long l0, l1, l2, l3, l4, l5;
    {
        int cnt = cnts[c];
        int r;
        r = lane;       l0 = (r < cnt) ? (((unsigned long long)minkey[c][r] << 9) | (unsigned)r) : ((0xFFFFFFFFull << 9) | (unsigned)r);
        r = lane + 64;  l1 = (r < cnt) ? (((unsigned long long)minkey[c][r] << 9) | (unsigned)r) : ((0xFFFFFFFFull << 9) | (unsigned)r);
        r = lane + 128; l2 = (r < cnt) ? (((unsigned long long)minkey[c][r] << 9) | (unsigned)r) : ((0xFFFFFFFFull << 9) | (unsigned)r);
        r = lane + 192; l3 = (r < cnt) ? (((unsigned long long)minkey[c][r] << 9) | (unsigned)r) : ((0xFFFFFFFFull << 9) | (unsigned)r);
        r = lane + 256; l4 = (r < cnt) ? (((unsigned long long)minkey[c][r] << 9) | (unsigned)r) : ((0xFFFFFFFFull << 9) | (unsigned)r);
        r = lane + 320; l5 = (r < cnt) ? (((unsigned long long)minkey[c][r] << 9) | (unsigned)r) : ((0xFFFFFFFFull << 9) | (unsigned)r);
    }
    int npos = 0, nbars = 0;
    float tot = 0.0f;
    for (int base = 0; base < m; base += 64) {
        int nn = m - base; if (nn > 64) nn = 64;
        unsigned long long myrec = elist[c][base + (lane < nn ? lane : 0)];
        for (int i2 = 0; i2 < nn; ++i2) {
            unsigned long long rec =
                (unsigned long long)__shfl((long long)myrec, i2, 64);   // uniform -> readlane
            int a = (int)((rec >> 9) & 511u), bb = (int)(rec & 511u);
            int ka = a >> 6, kb = bb >> 6;
            unsigned long long va = l0;
            va = (ka == 1) ? l1 : va; va = (ka == 2) ? l2 : va;
            va = (ka == 3) ? l3 : va; va = (ka == 4) ? l4 : va;
            va = (ka == 5) ? l5 : va;
            unsigned long long La = (unsigned long long)__shfl((long long)va, a & 63, 64);
            unsigned long long vb = l0;
            vb = (kb == 1) ? l1 : vb; vb = (kb == 2) ? l2 : vb;
            vb = (kb == 3) ? l3 : vb; vb = (kb == 4) ? l4 : vb;
            vb = (kb == 5) ? l5 : vb;
            unsigned long long Lb = (unsigned long long)__shfl((long long)vb, bb & 63, 64);
            if (La == Lb) continue;                  // same component (cycle edge)
            unsigned long long yg = (La > Lb) ? La : Lb;   // younger root
            unsigned long long el = (La > Lb) ? Lb : La;   // elder root
            float len = s2f((uint32_t)(rec >> 18)) - s2f((uint32_t)(yg >> 9));
            if (len > 0.0f) {
                if (lane == 0 && c >= 2 && nbars < 256)
                    poslist[c - 2][nbars] = __float_as_uint(len);
                nbars++; npos++; tot += len;
            }
            l0 = (l0 == yg) ? el : l0;               // flat relabel, no chains
            l1 = (l1 == yg) ? el : l1;
            l2 = (l2 == yg) ? el : l2;
            l3 = (l3 == yg) ? el : l3;
            l4 = (l4 == yg) ? el : l4;
            l5 = (l5 == yg) ? el : l5;
        }
    }
    if (lane == 0) {
        npos4[c] = npos;
        if (c >= 2) tot2[c - 2] = tot;
    }
    __syncthreads();                                // barrier #1

    // ---- combine: waves 2/3 sort own positive list + partial sum ----
    const int prior0 = npos4[0] + 1;                // +1: infinite essential bar
    const int prior1 = npos4[1];
    if (c >= 2) {
        uint32_t* arr = poslist[c - 2];             // positive floats: uint order ok
        for (int k = 2; k <= 256; k <<= 1) {
            for (int jj = k >> 1; jj > 0; jj >>= 1) {
                for (int i2 = lane; i2 < 256; i2 += 64) {
                    int l = i2 ^ jj;
                    if (l > i2) {
                        uint32_t A = arr[i2], B = arr[l];
                        bool up = ((i2 & k) == 0);
                        if ((A > B) == up) { arr[i2] = B; arr[l] = A; }
                    }
                }
                WSYNC();
            }
        }
        int pr = (c == 2) ? prior0 : prior1;
        if (pr > 256) pr = 256;
        float s = 0.0f;
        for (int i2 = lane; i2 < 256; i2 += 64)
            if (i2 >= 256 - pr) s += __uint_as_float(arr[i2]);
        #pragma unroll
        for (int o = 32; o > 0; o >>= 1) s += __shfl_xor(s, o, 64);
        if (lane == 0) psum[c - 2] = s;
    }
    __syncthreads();                                // barrier #2

    // ---- last block finalizes the mean (agent-scope atomics) ----
    if (tid == 0) {
        float loss = (tot2[0] - psum[0]) + (tot2[1] - psum[1]);
        __hip_atomic_store(&ws[8 + q], loss, __ATOMIC_RELAXED, __HIP_MEMORY_SCOPE_AGENT);
        int old = __hip_atomic_fetch_add((int*)ws, 1, __ATOMIC_ACQ_REL, __HIP_MEMORY_SCOPE_AGENT);
        if (old == 7) {
            float tt = 0.0f;
            for (int i = 0; i < 8; ++i)
                tt += __hip_atomic_load(&ws[8 + i], __ATOMIC_RELAXED, __HIP_MEMORY_SCOPE_AGENT);
            out[0] = tt * 0.125f;
        }
    }
}

extern "C" void kernel_launch(void* const* d_in, const int* in_sizes, int n_in,
                              void* d_out, int out_size, void* d_ws, size_t ws_size,
                              hipStream_t stream) {
    const float* x = (const float*)d_in[0];
    const float* y = (const float*)d_in[1];
    const int* offs = (const int*)d_in[2];
    hipMemsetAsync(d_ws, 0, 64, stream);            // zero the block counter
    toploss_one<<<8, 256, 0, stream>>>(x, y, offs, (float*)d_ws, (float*)d_out);
}

// Round 7
// 176.921 us; speedup vs baseline: 1.4948x; 1.4948x over previous
//
#include <hip/hip_runtime.h>
#include <stdint.h>

#define EMPTY 0xFFFFFFFFu
#define HSZ 2048
#define DREG 272       // floats per diagram region: [0]=npos,[1]=tot,[16..271]=poslist
typedef unsigned long long u64;

// In-wave phase sync (wave-local LDS ordering; no block barrier)
#define WSYNC() asm volatile("s_waitcnt lgkmcnt(0)" ::: "memory")

__device__ __forceinline__ uint32_t f2s(float f) {
    uint32_t u = __float_as_uint(f);
    return (u & 0x80000000u) ? ~u : (u | 0x80000000u);
}
__device__ __forceinline__ float s2f(uint32_t s) {
    uint32_t u = (s & 0x80000000u) ? (s & 0x7fffffffu) : ~s;
    return __uint_as_float(u);
}

// One block per diagram (bid = chunk*4 + c; c: 0=-y,1=+y,2=-x,3=+x).
// Front: basins (descent+jump), hash-dedup saddle edges (round-5 validated).
// Tail (wave 0, WSYNC-only): Boruvka -> MST edges (~cnt-1), 256-bitonic,
// elder-rule Kruskal with register labels + v_readlane (NO LDS in the chain).
// Combine: last block of each chunk-quad via device-scope atomics.
__global__ __launch_bounds__(256) void toploss_k(
        const float* __restrict__ xin, const float* __restrict__ yin,
        const int* __restrict__ offs, float* __restrict__ ws,
        float* __restrict__ out)
{
    __shared__ uint32_t key[1024];
    __shared__ unsigned short sd[1024];
    __shared__ unsigned short rnk[1024];   // rank map; reused as 'other' scratch
    __shared__ uint32_t minkey[384];
    __shared__ uint32_t hpair[HSZ], hwt[HSZ];
    __shared__ u64 elist[1024];
    __shared__ u64 mlist[512];
    __shared__ u64 best[384];
    __shared__ unsigned short par[384];
    __shared__ uint32_t poslist[256];
    __shared__ uint32_t lst[2][256];
    __shared__ float csum[2], tsh[2];
    __shared__ int prior_sh[2];
    __shared__ int cnt, ecnt, mcnt, npos_sh, win;
    __shared__ float tot_sh;

    const int bid = blockIdx.x;
    const int q = bid >> 2, c = bid & 3, b = q >> 1;
    const int tid = threadIdx.x;
    const int off0 = offs[q * 2], off1 = offs[q * 2 + 1];
    const float* img = (c >> 1) ? (xin + b * 160000) : (yin + b * 160000);
    const bool neg = ((c & 1) == 0);
    int* wsi = (int*)ws;
    float* chunkloss = ws + 16;

    if (tid == 0) { cnt = 0; ecnt = 0; mcnt = 0; }
    poslist[tid] = 0u;
    for (int s = tid; s < HSZ; s += 256) { hpair[s] = EMPTY; hwt[s] = EMPTY; }

    // ---- load chunk with +1.0 contour border; f2s(-v) == ~f2s(v) ----
    for (int s = 0; s < 4; ++s) {
        int u = tid + 256 * s;
        int i = u >> 5, j = u & 31;
        bool border = (i == 0) | (i == 31) | (j == 0) | (j == 31);
        float val = border ? 1.0f : img[(off0 + i - 1) * 400 + (off1 + j - 1)];
        uint32_t k = f2s(val);
        key[u] = neg ? ~k : k;
    }
    __syncthreads();

    // ---- steepest descent (strict total order (key,idx)) ----
    const int DI[6] = {-1, 1, 0, 0, 1, -1};
    const int DJ[6] = { 0, 0,-1, 1, 1, -1};
    for (int s = 0; s < 4; ++s) {
        int u = tid + 256 * s;
        int i = u >> 5, j = u & 31;
        u64 bestk = ((u64)key[u] << 10) | (unsigned)u;
        int bi = u;
        #pragma unroll
        for (int d = 0; d < 6; ++d) {
            int ni = i + DI[d], nj = j + DJ[d];
            if (ni < 0 || ni > 31 || nj < 0 || nj > 31) continue;
            int nb2 = (ni << 5) | nj;
            u64 kn = ((u64)key[nb2] << 10) | (unsigned)nb2;
            if (kn < bestk) { bestk = kn; bi = nb2; }
        }
        sd[u] = (unsigned short)bi;
    }
    __syncthreads();

    // ---- pointer jumping to basin min ----
    for (int r = 0; r < 10; ++r) {
        for (int s = 0; s < 4; ++s) { int u = tid + 256 * s; sd[u] = sd[sd[u]]; }
        __syncthreads();
    }

    // ---- dense-rank minima ----
    for (int s = 0; s < 4; ++s) {
        int u = tid + 256 * s;
        if (sd[u] == (unsigned short)u) {
            int r = atomicAdd(&cnt, 1);
            if (r < 384) { rnk[u] = (unsigned short)r; minkey[r] = key[u]; }
        }
    }
    __syncthreads();

    // ---- cross-basin edges, per-pair min weight via hash ----
    const int CDI[3] = {1, 0, 1}, CDJ[3] = {0, 1, 1};
    for (int s = 0; s < 4; ++s) {
        int u = tid + 256 * s;
        int i = u >> 5, j = u & 31;
        uint32_t ku = key[u];
        int sa = sd[u];
        #pragma unroll
        for (int d = 0; d < 3; ++d) {
            int ni = i + CDI[d], nj = j + CDJ[d];
            if (ni > 31 || nj > 31) continue;
            int nb2 = (ni << 5) | nj;
            int sb = sd[nb2];
            if (sa == sb) continue;
            uint32_t kn = key[nb2];
            uint32_t w = ku > kn ? ku : kn;
            int a = rnk[sa], bb = rnk[sb];
            if (a > bb) { int t = a; a = bb; bb = t; }
            uint32_t pk = ((uint32_t)a << 9) | (uint32_t)bb;
            uint32_t h = (pk * 2654435761u) >> 21;
            while (true) {
                uint32_t old = atomicCAS(&hpair[h], EMPTY, pk);
                if (old == EMPTY || old == pk) { atomicMin(&hwt[h], w); break; }
                h = (h + 1) & (HSZ - 1);
            }
        }
    }
    __syncthreads();

    // ---- compact hash -> edge list; init Boruvka parent ----
    for (int s = tid; s < HSZ; s += 256) {
        if (hpair[s] != EMPTY) {
            int e = atomicAdd(&ecnt, 1);
            elist[e] = ((u64)hwt[s] << 18) | hpair[s];
        }
    }
    __syncthreads();
    const int m_all = ecnt;
    for (int s = m_all + tid; s < 1024; s += 256) elist[s] = ~0ull;
    for (int s = tid; s < 384; s += 256) par[s] = (unsigned short)s;
    __syncthreads();

    // ================= wave-0 tail (no block barriers) =================
    if (tid < 64) {
        const int lane = tid;
        const int nb = cnt;

        // ---- Boruvka: find MST edges (strict (w,pair) order -> unique MST) ----
        for (int round = 0; round < 10; ++round) {
            for (int t = lane; t < 384; t += 64) best[t] = ~0ull;
            WSYNC();
            bool any = false;
            for (int t = lane; t < 1024; t += 64) {
                u64 rec = elist[t];
                if (rec == ~0ull) continue;
                int a = (int)((rec >> 9) & 511), b2 = (int)(rec & 511);
                int ra = par[a], rb = par[b2];
                if (ra == rb) elist[t] = ~0ull;
                else { atomicMin(&best[ra], rec); atomicMin(&best[rb], rec); any = true; }
            }
            WSYNC();
            if (__ballot(any) == 0ull) break;
            // pass A: snapshot each root's merge target (par is read-only here)
            for (int t = lane; t < 384; t += 64) {
                if (t < nb && par[t] == (unsigned short)t) {
                    u64 rec = best[t];
                    if (rec != ~0ull) {
                        int a = (int)((rec >> 9) & 511), b2 = (int)(rec & 511);
                        int ra = par[a], rb = par[b2];
                        rnk[t] = (unsigned short)((ra == t) ? rb : ra);
                    }
                }
            }
            WSYNC();
            // pass B: record MST edge once (mutual pairs pick identical rec) + repoint
            for (int t = lane; t < 384; t += 64) {
                if (t < nb && par[t] == (unsigned short)t) {
                    u64 rec = best[t];
                    if (rec != ~0ull) {
                        int other = rnk[t];
                        if (t < other || best[other] != rec) {
                            int mi = atomicAdd(&mcnt, 1);
                            if (mi < 512) mlist[mi] = rec;
                        }
                        par[t] = (unsigned short)other;
                    }
                }
            }
            WSYNC();
            // break mutual 2-cycles (benign races analyzed)
            for (int t = lane; t < 384; t += 64) {
                int p = par[t];
                if (par[p] == (unsigned short)t && t < p) par[t] = (unsigned short)t;
            }
            WSYNC();
            // flatten (in-place jumping is monotone)
            while (true) {
                bool ch = false;
                for (int t = lane; t < 384; t += 64) {
                    int p = par[t], p2 = par[p];
                    if (p2 != p) { par[t] = (unsigned short)p2; ch = true; }
                }
                WSYNC();
                if (__ballot(ch) == 0ull) break;
            }
        }

        // ---- sort MST edges ascending (in-wave bitonic) ----
        int mm = mcnt; if (mm > 512) mm = 512;
        const int msort = (mm <= 256) ? 256 : 512;
        for (int t = mm + lane; t < msort; t += 64) mlist[t] = ~0ull;
        WSYNC();
        for (int k = 2; k <= msort; k <<= 1) {
            for (int jj = k >> 1; jj > 0; jj >>= 1) {
                for (int i2 = lane; i2 < msort; i2 += 64) {
                    int l = i2 ^ jj;
                    if (l > i2) {
                        u64 A = mlist[i2], B = mlist[l];
                        bool up = ((i2 & k) == 0);
                        if ((A > B) == up) { mlist[i2] = B; mlist[l] = A; }
                    }
                }
                WSYNC();
            }
        }

        // ---- elder-rule Kruskal over MST edges; labels in regs, v_readlane ----
        u64 L0, L1, L2, L3, L4, L5;
        {
            int r;
            r = lane;       L0 = (r < nb) ? (((u64)minkey[r] << 9) | (unsigned)r) : ((0xFFFFFFFFull << 9) | (unsigned)r);
            r = lane + 64;  L1 = (r < nb) ? (((u64)minkey[r] << 9) | (unsigned)r) : ((0xFFFFFFFFull << 9) | (unsigned)r);
            r = lane + 128; L2 = (r < nb) ? (((u64)minkey[r] << 9) | (unsigned)r) : ((0xFFFFFFFFull << 9) | (unsigned)r);
            r = lane + 192; L3 = (r < nb) ? (((u64)minkey[r] << 9) | (unsigned)r) : ((0xFFFFFFFFull << 9) | (unsigned)r);
            r = lane + 256; L4 = (r < nb) ? (((u64)minkey[r] << 9) | (unsigned)r) : ((0xFFFFFFFFull << 9) | (unsigned)r);
            r = lane + 320; L5 = (r < nb) ? (((u64)minkey[r] << 9) | (unsigned)r) : ((0xFFFFFFFFull << 9) | (unsigned)r);
        }
        int npos = 0;
        float tot = 0.0f;
        bool done = false;
        for (int sl = 0; sl < 6 && !done; ++sl) {
            int base = sl * 64;
            if (base >= mm) break;
            u64 myrec = mlist[base + lane];
            for (int ln = 0; ln < 64; ++ln) {
                int e = base + ln;
                if (e >= mm) { done = true; break; }
                uint32_t rlo = __builtin_amdgcn_readlane((uint32_t)(myrec & 0xFFFFFFFFu), ln);
                uint32_t rhi = __builtin_amdgcn_readlane((uint32_t)(myrec >> 32), ln);
                u64 rec = ((u64)rhi << 32) | rlo;
                int a = (int)((rec >> 9) & 511), b2 = (int)(rec & 511);
                int ka = a >> 6, kb = b2 >> 6;
                u64 va = L0; va = (ka == 1) ? L1 : va; va = (ka == 2) ? L2 : va;
                va = (ka == 3) ? L3 : va; va = (ka == 4) ? L4 : va; va = (ka == 5) ? L5 : va;
                u64 vb = L0; vb = (kb == 1) ? L1 : vb; vb = (kb == 2) ? L2 : vb;
                vb = (kb == 3) ? L3 : vb; vb = (kb == 4) ? L4 : vb; vb = (kb == 5) ? L5 : vb;
                uint32_t alo = __builtin_amdgcn_readlane((uint32_t)(va & 0xFFFFFFFFu), a & 63);
                uint32_t ahi = __builtin_amdgcn_readlane((uint32_t)(va >> 32), a & 63);
                uint32_t blo = __builtin_amdgcn_readlane((uint32_t)(vb & 0xFFFFFFFFu), b2 & 63);
                uint32_t bhi = __builtin_amdgcn_readlane((uint32_t)(vb >> 32), b2 & 63);
                u64 La = ((u64)ahi << 32) | alo;
                u64 Lb = ((u64)bhi << 32) | blo;
                if (La == Lb) continue;               // duplicate mutual record
                u64 yg = (La > Lb) ? La : Lb;         // younger root label
                u64 el = (La > Lb) ? Lb : La;         // elder root label
                float len = s2f((uint32_t)(rec >> 18)) - s2f((uint32_t)(yg >> 9));
                if (len > 0.0f) {
                    if (lane == 0 && npos < 256) poslist[npos] = __float_as_uint(len);
                    ++npos; tot += len;
                }
                L0 = (L0 == yg) ? el : L0; L1 = (L1 == yg) ? el : L1;
                L2 = (L2 == yg) ? el : L2; L3 = (L3 == yg) ? el : L3;
                L4 = (L4 == yg) ? el : L4; L5 = (L5 == yg) ? el : L5;
            }
        }
        if (lane == 0) { npos_sh = npos; tot_sh = tot; }
    }
    __syncthreads();

    // ---- publish diagram results (device-scope atomics) ----
    float* reg = ws + 32 + bid * DREG;
    __hip_atomic_store(&reg[16 + tid], __uint_as_float(poslist[tid]),
                       __ATOMIC_RELAXED, __HIP_MEMORY_SCOPE_AGENT);
    if (tid == 0) {
        __hip_atomic_store(&reg[0], (float)npos_sh, __ATOMIC_RELAXED, __HIP_MEMORY_SCOPE_AGENT);
        __hip_atomic_store(&reg[1], tot_sh, __ATOMIC_RELAXED, __HIP_MEMORY_SCOPE_AGENT);
    }
    __syncthreads();
    if (tid == 0) {
        int old = __hip_atomic_fetch_add(&wsi[q], 1, __ATOMIC_ACQ_REL, __HIP_MEMORY_SCOPE_AGENT);
        win = (old == 3);
    }
    __syncthreads();

    // ---- last block of the chunk-quad combines ----
    if (win) {
        const float* r0 = ws + 32 + (q * 4 + 0) * DREG;
        const float* r1 = ws + 32 + (q * 4 + 1) * DREG;
        const float* r2 = ws + 32 + (q * 4 + 2) * DREG;
        const float* r3 = ws + 32 + (q * 4 + 3) * DREG;
        if (tid == 0) {
            prior_sh[0] = (int)__hip_atomic_load(&r0[0], __ATOMIC_RELAXED, __HIP_MEMORY_SCOPE_AGENT) + 1;
            prior_sh[1] = (int)__hip_atomic_load(&r1[0], __ATOMIC_RELAXED, __HIP_MEMORY_SCOPE_AGENT);
            tsh[0] = __hip_atomic_load(&r2[1], __ATOMIC_RELAXED, __HIP_MEMORY_SCOPE_AGENT);
            tsh[1] = __hip_atomic_load(&r3[1], __ATOMIC_RELAXED, __HIP_MEMORY_SCOPE_AGENT);
        }
        lst[0][tid] = __float_as_uint(__hip_atomic_load(&r2[16 + tid], __ATOMIC_RELAXED, __HIP_MEMORY_SCOPE_AGENT));
        lst[1][tid] = __float_as_uint(__hip_atomic_load(&r3[16 + tid], __ATOMIC_RELAXED, __HIP_MEMORY_SCOPE_AGENT));
        __syncthreads();
        const int w = tid >> 6, lane = tid & 63;
        if (w < 2) {
            uint32_t* arr = lst[w];          // positive floats: uint order = float order
            for (int k = 2; k <= 256; k <<= 1) {
                for (int jj = k >> 1; jj > 0; jj >>= 1) {
                    for (int i2 = lane; i2 < 256; i2 += 64) {
                        int l = i2 ^ jj;
                        if (l > i2) {
                            uint32_t A = arr[i2], B = arr[l];
                            bool up = ((i2 & k) == 0);
                            if ((A > B) == up) { arr[i2] = B; arr[l] = A; }
                        }
                    }
                    WSYNC();
                }
            }
            int pr = prior_sh[w]; if (pr > 256) pr = 256;
            float s = 0.0f;
            for (int i2 = lane; i2 < 256; i2 += 64)
                if (i2 >= 256 - pr) s += __uint_as_float(arr[i2]);
            #pragma unroll
            for (int o = 32; o > 0; o >>= 1) s += __shfl_xor(s, o, 64);
            if (lane == 0) csum[w] = s;
        }
        __syncthreads();
        if (tid == 0) {
            float loss = (tsh[0] - csum[0]) + (tsh[1] - csum[1]);
            __hip_atomic_store(&chunkloss[q], loss, __ATOMIC_RELAXED, __HIP_MEMORY_SCOPE_AGENT);
            int old2 = __hip_atomic_fetch_add(&wsi[8], 1, __ATOMIC_ACQ_REL, __HIP_MEMORY_SCOPE_AGENT);
            if (old2 == 7) {
                float tt = 0.0f;
                for (int i = 0; i < 8; ++i)
                    tt += __hip_atomic_load(&chunkloss[i], __ATOMIC_RELAXED, __HIP_MEMORY_SCOPE_AGENT);
                out[0] = tt * 0.125f;
            }
        }
    }
}

extern "C" void kernel_launch(void* const* d_in, const int* in_sizes, int n_in,
                              void* d_out, int out_size, void* d_ws, size_t ws_size,
                              hipStream_t stream) {
    const float* x = (const float*)d_in[0];
    const float* y = (const float*)d_in[1];
    const int* offs = (const int*)d_in[2];
    hipMemsetAsync(d_ws, 0, 64, stream);    // zero chunk counters + final counter
    toploss_k<<<32, 256, 0, stream>>>(x, y, offs, (float*)d_ws, (float*)d_out);
}

// Round 9
// 170.083 us; speedup vs baseline: 1.5549x; 1.0402x over previous
//
#include <hip/hip_runtime.h>
#include <stdint.h>

typedef unsigned long long u64;
#define DREG 272      // floats per diagram region: [0]=npos,[1]=tot,[16..271]=poslist

// In-wave phase sync (wave-local LDS ordering; no block barrier)
#define WSYNC() asm volatile("s_waitcnt lgkmcnt(0)" ::: "memory")

__device__ __forceinline__ uint32_t f2s(float f) {
    uint32_t u = __float_as_uint(f);
    return (u & 0x80000000u) ? ~u : (u | 0x80000000u);
}
__device__ __forceinline__ float s2f(uint32_t s) {
    uint32_t u = (s & 0x80000000u) ? (s & 0x7fffffffu) : ~s;
    return __uint_as_float(u);
}

// One block per diagram (bid = chunk*4 + c; c: 0=-y,1=+y,2=-x,3=+x).
// Basins (descent + adaptive jump) -> per-thread REGISTER edge list (rank-
// mapped, no hash/dedup) -> block-parallel Boruvka (implicit dedup via
// atomicMin) -> wave-0: sort ~nb-1 MST edges + elder-rule Kruskal with
// register labels + v_readlane. Combine: last block of each chunk-quad.
__global__ __launch_bounds__(256) void toploss_k(
        const float* __restrict__ xin, const float* __restrict__ yin,
        const int* __restrict__ offs, float* __restrict__ ws,
        float* __restrict__ out)
{
    __shared__ uint32_t key[1024];
    __shared__ unsigned short sd[1024];
    __shared__ unsigned short rnk[1024];   // vertex->rank; reused as Boruvka scratch
    __shared__ uint32_t minkey[384];
    __shared__ unsigned short par[384];
    __shared__ u64 best[384];
    __shared__ u64 mlist[512];
    __shared__ uint32_t poslist[256];
    __shared__ uint32_t lst[2][256];
    __shared__ float csum[2], tsh[2];
    __shared__ int prior_sh[2];
    __shared__ int cnt, mcnt, npos_sh, win;
    __shared__ float tot_sh;

    const int bid = blockIdx.x;
    const int q = bid >> 2, c = bid & 3, b = q >> 1;
    const int tid = threadIdx.x;
    const int off0 = offs[q * 2], off1 = offs[q * 2 + 1];
    const float* img = (c >> 1) ? (xin + b * 160000) : (yin + b * 160000);
    const bool neg = ((c & 1) == 0);
    int* wsi = (int*)ws;
    float* chunkloss = ws + 16;

    if (tid == 0) { cnt = 0; mcnt = 0; }
    poslist[tid] = 0u;
    for (int s = tid; s < 384; s += 256) par[s] = (unsigned short)s;

    // ---- load chunk with +1.0 contour border; f2s(-v) == ~f2s(v) ----
    for (int s = 0; s < 4; ++s) {
        int u = tid + 256 * s;
        int i = u >> 5, j = u & 31;
        bool border = (i == 0) | (i == 31) | (j == 0) | (j == 31);
        float val = border ? 1.0f : img[(off0 + i - 1) * 400 + (off1 + j - 1)];
        uint32_t k = f2s(val);
        key[u] = neg ? ~k : k;
    }
    __syncthreads();

    // ---- steepest descent (strict total order (key,idx)) ----
    const int DI[6] = {-1, 1, 0, 0, 1, -1};
    const int DJ[6] = { 0, 0,-1, 1, 1, -1};
    for (int s = 0; s < 4; ++s) {
        int u = tid + 256 * s;
        int i = u >> 5, j = u & 31;
        u64 bestk = ((u64)key[u] << 10) | (unsigned)u;
        int bi = u;
        #pragma unroll
        for (int d = 0; d < 6; ++d) {
            int ni = i + DI[d], nj = j + DJ[d];
            if (ni < 0 || ni > 31 || nj < 0 || nj > 31) continue;
            int nb2 = (ni << 5) | nj;
            u64 kn = ((u64)key[nb2] << 10) | (unsigned)nb2;
            if (kn < bestk) { bestk = kn; bi = nb2; }
        }
        sd[u] = (unsigned short)bi;
    }
    // ---- adaptive pointer jumping to basin min ----
    {
        bool ch = true;
        while (__syncthreads_or(ch ? 1 : 0)) {
            ch = false;
            for (int s = 0; s < 4; ++s) {
                int u = tid + 256 * s;
                int a = sd[u], a2 = sd[a];
                if (a2 != a) { sd[u] = (unsigned short)a2; ch = true; }
            }
        }
    }

    // ---- dense-rank minima ----
    for (int s = 0; s < 4; ++s) {
        int u = tid + 256 * s;
        if (sd[u] == (unsigned short)u) {
            int r = atomicAdd(&cnt, 1);
            if (r < 384) { rnk[u] = (unsigned short)r; minkey[r] = key[u]; }
        }
    }
    __syncthreads();

    // ---- per-thread REGISTER edge list (rank-mapped, canonical dirs) ----
    const int CDI[3] = {1, 0, 1}, CDJ[3] = {0, 1, 1};
    u64 earr[12];
    #pragma unroll
    for (int s = 0; s < 4; ++s) {
        int u = tid + 256 * s;
        int i = u >> 5, j = u & 31;
        uint32_t ku = key[u];
        int sa = sd[u];
        #pragma unroll
        for (int d = 0; d < 3; ++d) {
            u64 rec = ~0ull;
            int ni = i + CDI[d], nj = j + CDJ[d];
            if (ni <= 31 && nj <= 31) {
                int nb2 = (ni << 5) | nj;
                int sb = sd[nb2];
                if (sa != sb) {
                    uint32_t kn = key[nb2];
                    uint32_t w = ku > kn ? ku : kn;
                    int a = rnk[sa], b2 = rnk[sb];
                    if (a > b2) { int t = a; a = b2; b2 = t; }
                    rec = ((u64)w << 18) | ((u64)a << 9) | (u64)b2;
                }
            }
            earr[s * 3 + d] = rec;
        }
    }
    __syncthreads();

    // ---- block-parallel Boruvka: emit MST edges (strict order -> unique) ----
    const int nb = cnt;
    for (int round = 0; round < 10; ++round) {
        for (int t = tid; t < 384; t += 256) best[t] = ~0ull;
        __syncthreads();
        bool any = false;
        #pragma unroll
        for (int s = 0; s < 12; ++s) {
            u64 rec = earr[s];
            if (rec == ~0ull) continue;
            int a = (int)((rec >> 9) & 511), b2 = (int)(rec & 511);
            int ra = par[a], rb = par[b2];
            if (ra == rb) { earr[s] = ~0ull; continue; }
            atomicMin(&best[ra], rec);
            atomicMin(&best[rb], rec);
            any = true;
        }
        if (!__syncthreads_or(any ? 1 : 0)) break;
        // pass A: snapshot each root's merge target (par read-only here)
        for (int t = tid; t < 384; t += 256) {
            if (t < nb && par[t] == (unsigned short)t) {
                u64 rec = best[t];
                if (rec != ~0ull) {
                    int a = (int)((rec >> 9) & 511), b2 = (int)(rec & 511);
                    int ra = par[a], rb = par[b2];
                    rnk[t] = (unsigned short)((ra == t) ? rb : ra);
                }
            }
        }
        __syncthreads();
        // pass B: record MST edge once (mutual pairs dedup) + repoint
        for (int t = tid; t < 384; t += 256) {
            if (t < nb && par[t] == (unsigned short)t) {
                u64 rec = best[t];
                if (rec != ~0ull) {
                    int other = rnk[t];
                    if (t < other || best[other] != rec) {
                        int mi = atomicAdd(&mcnt, 1);
                        if (mi < 512) mlist[mi] = rec;
                    }
                    par[t] = (unsigned short)other;
                }
            }
        }
        __syncthreads();
        // break mutual 2-cycles (t<p keeps t as root)
        for (int t = tid; t < 384; t += 256) {
            int p = par[t];
            if (par[p] == (unsigned short)t && t < p) par[t] = (unsigned short)t;
        }
        // flatten (first or-barrier orders the 2-cycle-break writes)
        bool ch = true;
        while (__syncthreads_or(ch ? 1 : 0)) {
            ch = false;
            for (int t = tid; t < 384; t += 256) {
                int p = par[t], p2 = par[p];
                if (p2 != p) { par[t] = (unsigned short)p2; ch = true; }
            }
        }
    }
    __syncthreads();

    // ================= wave-0 tail (WSYNC only) =================
    if (tid < 64) {
        const int lane = tid;
        int mm = mcnt; if (mm > 512) mm = 512;
        const int msort = (mm <= 256) ? 256 : 512;
        for (int t = mm + lane; t < msort; t += 64) mlist[t] = ~0ull;
        WSYNC();
        // in-wave bitonic sort ascending by (weight, pair)
        for (int k = 2; k <= msort; k <<= 1) {
            for (int jj = k >> 1; jj > 0; jj >>= 1) {
                for (int i2 = lane; i2 < msort; i2 += 64) {
                    int l = i2 ^ jj;
                    if (l > i2) {
                        u64 A = mlist[i2], B = mlist[l];
                        bool up = ((i2 & k) == 0);
                        if ((A > B) == up) { mlist[i2] = B; mlist[l] = A; }
                    }
                }
                WSYNC();
            }
        }

        // elder-rule Kruskal over MST edges; labels in regs, v_readlane
        u64 L0, L1, L2, L3, L4, L5;
        {
            int r;
            r = lane;       L0 = (r < nb) ? (((u64)minkey[r] << 9) | (unsigned)r) : ((0xFFFFFFFFull << 9) | (unsigned)r);
            r = lane + 64;  L1 = (r < nb) ? (((u64)minkey[r] << 9) | (unsigned)r) : ((0xFFFFFFFFull << 9) | (unsigned)r);
            r = lane + 128; L2 = (r < nb) ? (((u64)minkey[r] << 9) | (unsigned)r) : ((0xFFFFFFFFull << 9) | (unsigned)r);
            r = lane + 192; L3 = (r < nb) ? (((u64)minkey[r] << 9) | (unsigned)r) : ((0xFFFFFFFFull << 9) | (unsigned)r);
            r = lane + 256; L4 = (r < nb) ? (((u64)minkey[r] << 9) | (unsigned)r) : ((0xFFFFFFFFull << 9) | (unsigned)r);
            r = lane + 320; L5 = (r < nb) ? (((u64)minkey[r] << 9) | (unsigned)r) : ((0xFFFFFFFFull << 9) | (unsigned)r);
        }
        int npos = 0;
        float tot = 0.0f;
        bool done = false;
        for (int sl = 0; sl < 6 && !done; ++sl) {
            int base = sl * 64;
            if (base >= mm) break;
            u64 myrec = mlist[base + lane];
            for (int ln = 0; ln < 64; ++ln) {
                int e = base + ln;
                if (e >= mm) { done = true; break; }
                uint32_t rlo = __builtin_amdgcn_readlane((uint32_t)(myrec & 0xFFFFFFFFu), ln);
                uint32_t rhi = __builtin_amdgcn_readlane((uint32_t)(myrec >> 32), ln);
                u64 rec = ((u64)rhi << 32) | rlo;
                int a = (int)((rec >> 9) & 511), b2 = (int)(rec & 511);
                int ka = a >> 6, kb = b2 >> 6;
                u64 va = L0; va = (ka == 1) ? L1 : va; va = (ka == 2) ? L2 : va;
                va = (ka == 3) ? L3 : va; va = (ka == 4) ? L4 : va; va = (ka == 5) ? L5 : va;
                u64 vb = L0; vb = (kb == 1) ? L1 : vb; vb = (kb == 2) ? L2 : vb;
                vb = (kb == 3) ? L3 : vb; vb = (kb == 4) ? L4 : vb; vb = (kb == 5) ? L5 : vb;
                uint32_t alo = __builtin_amdgcn_readlane((uint32_t)(va & 0xFFFFFFFFu), a & 63);
                uint32_t ahi = __builtin_amdgcn_readlane((uint32_t)(va >> 32), a & 63);
                uint32_t blo = __builtin_amdgcn_readlane((uint32_t)(vb & 0xFFFFFFFFu), b2 & 63);
                uint32_t bhi = __builtin_amdgcn_readlane((uint32_t)(vb >> 32), b2 & 63);
                u64 La = ((u64)ahi << 32) | alo;
                u64 Lb = ((u64)bhi << 32) | blo;
                if (La == Lb) continue;               // duplicate mutual record
                u64 yg = (La > Lb) ? La : Lb;         // younger root label
                u64 el = (La > Lb) ? Lb : La;         // elder root label
                float len = s2f((uint32_t)(rec >> 18)) - s2f((uint32_t)(yg >> 9));
                if (len > 0.0f) {
                    if (lane == 0 && npos < 256) poslist[npos] = __float_as_uint(len);
                    ++npos; tot += len;
                }
                L0 = (L0 == yg) ? el : L0; L1 = (L1 == yg) ? el : L1;
                L2 = (L2 == yg) ? el : L2; L3 = (L3 == yg) ? el : L3;
                L4 = (L4 == yg) ? el : L4; L5 = (L5 == yg) ? el : L5;
            }
        }
        if (lane == 0) { npos_sh = npos; tot_sh = tot; }
    }
    __syncthreads();

    // ---- publish diagram results (device-scope atomics) ----
    float* reg = ws + 32 + bid * DREG;
    __hip_atomic_store(&reg[16 + tid], __uint_as_float(poslist[tid]),
                       __ATOMIC_RELAXED, __HIP_MEMORY_SCOPE_AGENT);
    if (tid == 0) {
        __hip_atomic_store(&reg[0], (float)npos_sh, __ATOMIC_RELAXED, __HIP_MEMORY_SCOPE_AGENT);
        __hip_atomic_store(&reg[1], tot_sh, __ATOMIC_RELAXED, __HIP_MEMORY_SCOPE_AGENT);
    }
    __syncthreads();
    if (tid == 0) {
        int old = __hip_atomic_fetch_add(&wsi[q], 1, __ATOMIC_ACQ_REL, __HIP_MEMORY_SCOPE_AGENT);
        win = (old == 3);
    }
    __syncthreads();

    // ---- last block of the chunk-quad combines ----
    if (win) {
        const float* r0 = ws + 32 + (q * 4 + 0) * DREG;
        const float* r1 = ws + 32 + (q * 4 + 1) * DREG;
        const float* r2 = ws + 32 + (q * 4 + 2) * DREG;
        const float* r3 = ws + 32 + (q * 4 + 3) * DREG;
        if (tid == 0) {
            prior_sh[0] = (int)__hip_atomic_load(&r0[0], __ATOMIC_RELAXED, __HIP_MEMORY_SCOPE_AGENT) + 1;
            prior_sh[1] = (int)__hip_atomic_load(&r1[0], __ATOMIC_RELAXED, __HIP_MEMORY_SCOPE_AGENT);
            tsh[0] = __hip_atomic_load(&r2[1], __ATOMIC_RELAXED, __HIP_MEMORY_SCOPE_AGENT);
            tsh[1] = __hip_atomic_load(&r3[1], __ATOMIC_RELAXED, __HIP_MEMORY_SCOPE_AGENT);
        }
        lst[0][tid] = __float_as_uint(__hip_atomic_load(&r2[16 + tid], __ATOMIC_RELAXED, __HIP_MEMORY_SCOPE_AGENT));
        lst[1][tid] = __float_as_uint(__hip_atomic_load(&r3[16 + tid], __ATOMIC_RELAXED, __HIP_MEMORY_SCOPE_AGENT));
        __syncthreads();
        const int w = tid >> 6, lane = tid & 63;
        if (w < 2) {
            uint32_t* arr = lst[w];          // positive floats: uint order = float order
            for (int k = 2; k <= 256; k <<= 1) {
                for (int jj = k >> 1; jj > 0; jj >>= 1) {
                    for (int i2 = lane; i2 < 256; i2 += 64) {
                        int l = i2 ^ jj;
                        if (l > i2) {
                            uint32_t A = arr[i2], B = arr[l];
                            bool up = ((i2 & k) == 0);
                            if ((A > B) == up) { arr[i2] = B; arr[l] = A; }
                        }
                    }
                    WSYNC();
                }
            }
            int pr = prior_sh[w]; if (pr > 256) pr = 256;
            float s = 0.0f;
            for (int i2 = lane; i2 < 256; i2 += 64)
                if (i2 >= 256 - pr) s += __uint_as_float(arr[i2]);
            #pragma unroll
            for (int o = 32; o > 0; o >>= 1) s += __shfl_xor(s, o, 64);
            if (lane == 0) csum[w] = s;
        }
        __syncthreads();
        if (tid == 0) {
            float loss = (tsh[0] - csum[0]) + (tsh[1] - csum[1]);
            __hip_atomic_store(&chunkloss[q], loss, __ATOMIC_RELAXED, __HIP_MEMORY_SCOPE_AGENT);
            int old2 = __hip_atomic_fetch_add(&wsi[8], 1, __ATOMIC_ACQ_REL, __HIP_MEMORY_SCOPE_AGENT);
            if (old2 == 7) {
                float tt = 0.0f;
                for (int i = 0; i < 8; ++i)
                    tt += __hip_atomic_load(&chunkloss[i], __ATOMIC_RELAXED, __HIP_MEMORY_SCOPE_AGENT);
                out[0] = tt * 0.125f;
            }
        }
    }
}

extern "C" void kernel_launch(void* const* d_in, const int* in_sizes, int n_in,
                              void* d_out, int out_size, void* d_ws, size_t ws_size,
                              hipStream_t stream) {
    const float* x = (const float*)d_in[0];
    const float* y = (const float*)d_in[1];
    const int* offs = (const int*)d_in[2];
    hipMemsetAsync(d_ws, 0, 64, stream);    // zero chunk counters + final counter
    toploss_k<<<32, 256, 0, stream>>>(x, y, offs, (float*)d_ws, (float*)d_out);
}

// Round 10
// 123.981 us; speedup vs baseline: 2.1331x; 1.3718x over previous
//
#include <hip/hip_runtime.h>
#include <stdint.h>

typedef unsigned long long u64;
#define INFK 0xFFFFFFFFu
#define DREG 264   // floats per diagram region: [0]=npos, [4..259]=poslist

// In-wave phase sync (wave-local LDS ordering; no block barrier)
#define WSYNC() asm volatile("s_waitcnt lgkmcnt(0)" ::: "memory")

__device__ __forceinline__ uint32_t f2s(float f) {
    uint32_t u = __float_as_uint(f);
    return (u & 0x80000000u) ? ~u : (u | 0x80000000u);
}
__device__ __forceinline__ float s2f(uint32_t s) {
    uint32_t u = (s & 0x80000000u) ? (s & 0x7fffffffu) : ~s;
    return __uint_as_float(u);
}

// Lock-free triplet merge-tree insertion (validated rounds 3/4, absmax 0.0).
__device__ __forceinline__ void tmerge(u64* trip, const u64* bku,
                                       int a, int b, uint32_t w) {
    while (true) {
        int ra = a;
        while (true) {
            u64 t = *(volatile u64*)&trip[ra];
            uint32_t sv = (uint32_t)(t >> 32);
            if (sv > w) break;
            ra = (int)(t & 0xFFFFu);
        }
        int rb = b;
        while (true) {
            u64 t = *(volatile u64*)&trip[rb];
            uint32_t sv = (uint32_t)(t >> 32);
            if (sv > w) break;
            rb = (int)(t & 0xFFFFu);
        }
        if (ra == rb) return;
        int y, e;
        if (bku[ra] < bku[rb]) { e = ra; y = rb; } else { e = rb; y = ra; }
        u64 old = *(volatile u64*)&trip[y];
        uint32_t sy = (uint32_t)(old >> 32);
        if (sy <= w) continue;                 // concurrent change; re-walk
        u64 nw = ((u64)w << 32) | (unsigned)e;
        if (atomicCAS(&trip[y], old, nw) == old) {
            if (sy == INFK) return;            // no displaced fact
            a = y; b = (int)(old & 0xFFFFu); w = sy;   // re-insert displaced fact
        }
    }
}

// One block per diagram (bid = chunk*4 + c; c: 0=-y,1=+y,2=-x,3=+x).
// Basins: steepest descent + per-thread register chase w/ path compression
// (1 barrier, no doubling rounds). Pairing: parallel lock-free tmerge over
// all cross-basin grid edges (no hash/sort/Boruvka/Kruskal). Combine: last
// block of each chunk-quad; all sums from sorted lists (deterministic).
__global__ __launch_bounds__(256) void toploss_k(
        const float* __restrict__ xin, const float* __restrict__ yin,
        const int* __restrict__ offs, float* __restrict__ ws,
        float* __restrict__ out)
{
    __shared__ uint32_t key[1024];
    __shared__ unsigned short sd[1024];
    __shared__ unsigned short rnk[1024];
    __shared__ u64 bku[384];       // rank -> birth key (key<<10 | vertex)
    __shared__ u64 trip[384];      // rank -> (death<<32 | elder_rank)
    __shared__ uint32_t poslist[256];
    __shared__ uint32_t lst[2][256];
    __shared__ float csum[2];
    __shared__ int prior_sh[2];
    __shared__ int cnt, nslot, win;

    const int bid = blockIdx.x;
    const int q = bid >> 2, c = bid & 3, b = q >> 1;
    const int tid = threadIdx.x;
    const int off0 = offs[q * 2], off1 = offs[q * 2 + 1];
    const float* img = (c >> 1) ? (xin + b * 160000) : (yin + b * 160000);
    const bool neg = ((c & 1) == 0);
    int* wsi = (int*)ws;
    float* chunkloss = ws + 16;

    if (tid == 0) { cnt = 0; nslot = 0; }
    poslist[tid] = 0u;

    // ---- load chunk with +1.0 contour border; f2s(-v) == ~f2s(v) ----
    uint32_t kreg[4];
    for (int s = 0; s < 4; ++s) {
        int u = tid + 256 * s;
        int i = u >> 5, j = u & 31;
        bool border = (i == 0) | (i == 31) | (j == 0) | (j == 31);
        float val = border ? 1.0f : img[(off0 + i - 1) * 400 + (off1 + j - 1)];
        uint32_t k = f2s(val);
        k = neg ? ~k : k;
        kreg[s] = k;
        key[u] = k;
    }
    __syncthreads();

    // ---- steepest descent (strict total order (key,idx)) ----
    const int DI[6] = {-1, 1, 0, 0, 1, -1};
    const int DJ[6] = { 0, 0,-1, 1, 1, -1};
    for (int s = 0; s < 4; ++s) {
        int u = tid + 256 * s;
        int i = u >> 5, j = u & 31;
        u64 bestk = ((u64)kreg[s] << 10) | (unsigned)u;
        int bi = u;
        #pragma unroll
        for (int d = 0; d < 6; ++d) {
            int ni = i + DI[d], nj = j + DJ[d];
            if (ni < 0 || ni > 31 || nj < 0 || nj > 31) continue;
            int nb2 = (ni << 5) | nj;
            u64 kn = ((u64)key[nb2] << 10) | (unsigned)nb2;
            if (kn < bestk) { bestk = kn; bi = nb2; }
        }
        sd[u] = (unsigned short)bi;
    }
    __syncthreads();

    // ---- register chase to basin min, in-place path compression ----
    // (compression writes are monotone shortcuts; u16 LDS writes don't tear)
    for (int s = 0; s < 4; ++s) {
        int u = tid + 256 * s;
        int r = sd[u];
        int p = sd[r];
        while (p != r) { r = p; p = sd[r]; }
        sd[u] = (unsigned short)r;
    }
    __syncthreads();

    // ---- dense-rank minima; init triplets ----
    for (int s = 0; s < 4; ++s) {
        int u = tid + 256 * s;
        if (sd[u] == (unsigned short)u) {
            int r = atomicAdd(&cnt, 1);
            if (r < 384) {
                rnk[u] = (unsigned short)r;
                bku[r] = ((u64)kreg[s] << 10) | (unsigned)u;
                trip[r] = ((u64)INFK << 32) | (unsigned)r;
            }
        }
    }
    __syncthreads();

    // ---- lock-free triplet merges over all cross-basin edges ----
    const int CDI[3] = {1, 0, 1}, CDJ[3] = {0, 1, 1};
    for (int s = 0; s < 4; ++s) {
        int u = tid + 256 * s;
        int i = u >> 5, j = u & 31;
        uint32_t ku = kreg[s];
        int sa = sd[u];
        #pragma unroll
        for (int d = 0; d < 3; ++d) {
            int ni = i + CDI[d], nj = j + CDJ[d];
            if (ni > 31 || nj > 31) continue;
            int nb2 = (ni << 5) | nj;
            int sb = sd[nb2];
            if (sa == sb) continue;
            uint32_t kn = key[nb2];
            uint32_t w = ku > kn ? ku : kn;
            tmerge(trip, bku, rnk[sa], rnk[sb], w);
        }
    }
    __syncthreads();

    // ---- collect positive bar lengths ----
    for (int t = tid; t < 384; t += 256) {
        if (t < cnt) {
            u64 tt = trip[t];
            uint32_t sv = (uint32_t)(tt >> 32);
            if (sv != INFK) {
                float len = s2f(sv) - s2f((uint32_t)(bku[t] >> 10));
                if (len > 0.0f) {
                    int sl = atomicAdd(&nslot, 1);
                    if (sl < 256) poslist[sl] = __float_as_uint(len);
                }
            }
        }
    }
    __syncthreads();

    // ---- publish diagram results (device-scope atomics) ----
    float* reg = ws + 32 + bid * DREG;
    __hip_atomic_store(&reg[4 + tid], __uint_as_float(poslist[tid]),
                       __ATOMIC_RELAXED, __HIP_MEMORY_SCOPE_AGENT);
    if (tid == 0)
        __hip_atomic_store(&reg[0], (float)nslot, __ATOMIC_RELAXED, __HIP_MEMORY_SCOPE_AGENT);
    __syncthreads();
    if (tid == 0) {
        int old = __hip_atomic_fetch_add(&wsi[q], 1, __ATOMIC_ACQ_REL, __HIP_MEMORY_SCOPE_AGENT);
        win = (old == 3);
    }
    __syncthreads();

    // ---- last block of the chunk-quad combines (all-deterministic sums) ----
    if (win) {
        const float* r0 = ws + 32 + (q * 4 + 0) * DREG;
        const float* r1 = ws + 32 + (q * 4 + 1) * DREG;
        const float* r2 = ws + 32 + (q * 4 + 2) * DREG;
        const float* r3 = ws + 32 + (q * 4 + 3) * DREG;
        if (tid == 0) {
            prior_sh[0] = (int)__hip_atomic_load(&r0[0], __ATOMIC_RELAXED, __HIP_MEMORY_SCOPE_AGENT) + 1;
            prior_sh[1] = (int)__hip_atomic_load(&r1[0], __ATOMIC_RELAXED, __HIP_MEMORY_SCOPE_AGENT);
        }
        lst[0][tid] = __float_as_uint(__hip_atomic_load(&r2[4 + tid], __ATOMIC_RELAXED, __HIP_MEMORY_SCOPE_AGENT));
        lst[1][tid] = __float_as_uint(__hip_atomic_load(&r3[4 + tid], __ATOMIC_RELAXED, __HIP_MEMORY_SCOPE_AGENT));
        __syncthreads();
        const int w = tid >> 6, lane = tid & 63;
        if (w < 2) {
            uint32_t* arr = lst[w];        // positive floats: uint order = float order
            for (int k = 2; k <= 256; k <<= 1) {
                for (int jj = k >> 1; jj > 0; jj >>= 1) {
                    for (int i2 = lane; i2 < 256; i2 += 64) {
                        int l = i2 ^ jj;
                        if (l > i2) {
                            uint32_t A = arr[i2], B = arr[l];
                            bool up = ((i2 & k) == 0);
                            if ((A > B) == up) { arr[i2] = B; arr[l] = A; }
                        }
                    }
                    WSYNC();
                }
            }
            // loss_part = sum of the (256 - prior) smallest entries (zeros pad)
            int pr = prior_sh[w]; if (pr > 256) pr = 256;
            int keep = 256 - pr;
            float s = 0.0f;
            for (int i2 = lane; i2 < 256; i2 += 64)
                if (i2 < keep) s += __uint_as_float(arr[i2]);
            #pragma unroll
            for (int o = 32; o > 0; o >>= 1) s += __shfl_xor(s, o, 64);
            if (lane == 0) csum[w] = s;
        }
        __syncthreads();
        if (tid == 0) {
            float loss = csum[0] + csum[1];
            __hip_atomic_store(&chunkloss[q], loss, __ATOMIC_RELAXED, __HIP_MEMORY_SCOPE_AGENT);
            int old2 = __hip_atomic_fetch_add(&wsi[8], 1, __ATOMIC_ACQ_REL, __HIP_MEMORY_SCOPE_AGENT);
            if (old2 == 7) {
                float tt = 0.0f;
                for (int i = 0; i < 8; ++i)
                    tt += __hip_atomic_load(&chunkloss[i], __ATOMIC_RELAXED, __HIP_MEMORY_SCOPE_AGENT);
                out[0] = tt * 0.125f;
            }
        }
    }
}

extern "C" void kernel_launch(void* const* d_in, const int* in_sizes, int n_in,
                              void* d_out, int out_size, void* d_ws, size_t ws_size,
                              hipStream_t stream) {
    const float* x = (const float*)d_in[0];
    const float* y = (const float*)d_in[1];
    const int* offs = (const int*)d_in[2];
    hipMemsetAsync(d_ws, 0, 64, stream);    // zero chunk counters + final counter
    toploss_k<<<32, 256, 0, stream>>>(x, y, offs, (float*)d_ws, (float*)d_out);
}

// Round 11
// 123.047 us; speedup vs baseline: 2.1493x; 1.0076x over previous
//
#include <hip/hip_runtime.h>
#include <stdint.h>

typedef unsigned long long u64;
#define INFK 0xFFFFFFFFu
#define DREG 264   // floats per diagram region: [0]=npos, [4..259]=poslist

// In-wave phase sync (wave-local LDS ordering; no block barrier)
#define WSYNC() asm volatile("s_waitcnt lgkmcnt(0)" ::: "memory")

__device__ __forceinline__ uint32_t f2s(float f) {
    uint32_t u = __float_as_uint(f);
    return (u & 0x80000000u) ? ~u : (u | 0x80000000u);
}
__device__ __forceinline__ float s2f(uint32_t s) {
    uint32_t u = (s & 0x80000000u) ? (s & 0x7fffffffu) : ~s;
    return __uint_as_float(u);
}

// Lock-free triplet merge-tree insertion (validated rounds 3/4/10, absmax 0.0).
__device__ __forceinline__ void tmerge(u64* trip, const u64* bku,
                                       int a, int b, uint32_t w) {
    while (true) {
        int ra = a;
        while (true) {
            u64 t = *(volatile u64*)&trip[ra];
            uint32_t sv = (uint32_t)(t >> 32);
            if (sv > w) break;
            ra = (int)(t & 0xFFFFu);
        }
        int rb = b;
        while (true) {
            u64 t = *(volatile u64*)&trip[rb];
            uint32_t sv = (uint32_t)(t >> 32);
            if (sv > w) break;
            rb = (int)(t & 0xFFFFu);
        }
        if (ra == rb) return;
        int y, e;
        if (bku[ra] < bku[rb]) { e = ra; y = rb; } else { e = rb; y = ra; }
        u64 old = *(volatile u64*)&trip[y];
        uint32_t sy = (uint32_t)(old >> 32);
        if (sy <= w) continue;                 // concurrent change; re-walk
        u64 nw = ((u64)w << 32) | (unsigned)e;
        if (atomicCAS(&trip[y], old, nw) == old) {
            if (sy == INFK) return;            // no displaced fact
            a = y; b = (int)(old & 0xFFFFu); w = sy;   // re-insert displaced fact
        }
    }
}

// One block per diagram (bid = chunk*4 + c; c: 0=-y,1=+y,2=-x,3=+x).
// Front only: basins (descent + 4-way-interleaved register chase), dense
// rank, lock-free tmerge, collect positives, plain stores to ws.
__global__ __launch_bounds__(256) void pd_kernel(
        const float* __restrict__ xin, const float* __restrict__ yin,
        const int* __restrict__ offs, float* __restrict__ ws)
{
    __shared__ uint32_t key[1024];
    __shared__ unsigned short sd[1024];
    __shared__ unsigned short rnk[1024];
    __shared__ u64 bku[384];       // rank -> birth key (key<<10 | vertex)
    __shared__ u64 trip[384];      // rank -> (death<<32 | elder_rank)
    __shared__ uint32_t poslist[256];
    __shared__ int cnt, nslot;

    const int bid = blockIdx.x;
    const int q = bid >> 2, c = bid & 3, b = q >> 1;
    const int tid = threadIdx.x;
    const int off0 = offs[q * 2], off1 = offs[q * 2 + 1];
    const float* img = (c >> 1) ? (xin + b * 160000) : (yin + b * 160000);
    const bool neg = ((c & 1) == 0);

    if (tid == 0) { cnt = 0; nslot = 0; }
    poslist[tid] = 0u;

    // ---- load chunk with +1.0 contour border; f2s(-v) == ~f2s(v) ----
    uint32_t kreg[4];
    for (int s = 0; s < 4; ++s) {
        int u = tid + 256 * s;
        int i = u >> 5, j = u & 31;
        bool border = (i == 0) | (i == 31) | (j == 0) | (j == 31);
        float val = border ? 1.0f : img[(off0 + i - 1) * 400 + (off1 + j - 1)];
        uint32_t k = f2s(val);
        k = neg ? ~k : k;
        kreg[s] = k;
        key[u] = k;
    }
    __syncthreads();

    // ---- steepest descent (strict total order (key,idx)) ----
    const int DI[6] = {-1, 1, 0, 0, 1, -1};
    const int DJ[6] = { 0, 0,-1, 1, 1, -1};
    for (int s = 0; s < 4; ++s) {
        int u = tid + 256 * s;
        int i = u >> 5, j = u & 31;
        u64 bestk = ((u64)kreg[s] << 10) | (unsigned)u;
        int bi = u;
        #pragma unroll
        for (int d = 0; d < 6; ++d) {
            int ni = i + DI[d], nj = j + DJ[d];
            if (ni < 0 || ni > 31 || nj < 0 || nj > 31) continue;
            int nb2 = (ni << 5) | nj;
            u64 kn = ((u64)key[nb2] << 10) | (unsigned)nb2;
            if (kn < bestk) { bestk = kn; bi = nb2; }
        }
        sd[u] = (unsigned short)bi;
    }
    __syncthreads();

    // ---- 4-way interleaved register chase to basin min (ILP on the
    //      dependent LDS chains), then one compression write per vertex ----
    {
        const int u0 = tid, u1 = tid + 256, u2 = tid + 512, u3 = tid + 768;
        int r0 = sd[u0], r1 = sd[u1], r2 = sd[u2], r3 = sd[u3];
        while (true) {
            int p0 = sd[r0], p1 = sd[r1], p2 = sd[r2], p3 = sd[r3];
            if (p0 == r0 && p1 == r1 && p2 == r2 && p3 == r3) break;
            r0 = p0; r1 = p1; r2 = p2; r3 = p3;
        }
        sd[u0] = (unsigned short)r0;   // monotone shortcut writes (benign races)
        sd[u1] = (unsigned short)r1;
        sd[u2] = (unsigned short)r2;
        sd[u3] = (unsigned short)r3;
    }
    __syncthreads();

    // ---- dense-rank minima; init triplets ----
    for (int s = 0; s < 4; ++s) {
        int u = tid + 256 * s;
        if (sd[u] == (unsigned short)u) {
            int r = atomicAdd(&cnt, 1);
            if (r < 384) {
                rnk[u] = (unsigned short)r;
                bku[r] = ((u64)kreg[s] << 10) | (unsigned)u;
                trip[r] = ((u64)INFK << 32) | (unsigned)r;
            }
        }
    }
    __syncthreads();

    // ---- lock-free triplet merges over all cross-basin edges ----
    const int CDI[3] = {1, 0, 1}, CDJ[3] = {0, 1, 1};
    for (int s = 0; s < 4; ++s) {
        int u = tid + 256 * s;
        int i = u >> 5, j = u & 31;
        uint32_t ku = kreg[s];
        int sa = sd[u];
        #pragma unroll
        for (int d = 0; d < 3; ++d) {
            int ni = i + CDI[d], nj = j + CDJ[d];
            if (ni > 31 || nj > 31) continue;
            int nb2 = (ni << 5) | nj;
            int sb = sd[nb2];
            if (sa == sb) continue;
            uint32_t kn = key[nb2];
            uint32_t w = ku > kn ? ku : kn;
            tmerge(trip, bku, rnk[sa], rnk[sb], w);
        }
    }
    __syncthreads();

    // ---- collect positive bar lengths ----
    for (int t = tid; t < 384; t += 256) {
        if (t < cnt) {
            u64 tt = trip[t];
            uint32_t sv = (uint32_t)(tt >> 32);
            if (sv != INFK) {
                float len = s2f(sv) - s2f((uint32_t)(bku[t] >> 10));
                if (len > 0.0f) {
                    int sl = atomicAdd(&nslot, 1);
                    if (sl < 256) poslist[sl] = __float_as_uint(len);
                }
            }
        }
    }
    __syncthreads();

    // ---- publish (plain stores; k2 is stream-ordered after us) ----
    float* reg = ws + 32 + bid * DREG;
    reg[4 + tid] = __uint_as_float(poslist[tid]);
    if (tid == 0) reg[0] = (float)nslot;
}

// One block per chunk: combine 4 diagrams -> chunk loss; last block -> mean.
__global__ __launch_bounds__(256) void loss_kernel(float* __restrict__ ws,
                                                   float* __restrict__ out)
{
    __shared__ uint32_t lst[2][256];
    __shared__ float csum[2];
    __shared__ int prior_sh[2];

    const int q = blockIdx.x, tid = threadIdx.x;
    int* wsi = (int*)ws;
    float* chunkloss = ws + 16;
    const float* r0 = ws + 32 + (q * 4 + 0) * DREG;
    const float* r1 = ws + 32 + (q * 4 + 1) * DREG;
    const float* r2 = ws + 32 + (q * 4 + 2) * DREG;
    const float* r3 = ws + 32 + (q * 4 + 3) * DREG;

    if (tid == 0) {
        prior_sh[0] = (int)r0[0] + 1;   // +1: infinite essential dim-0 bar
        prior_sh[1] = (int)r1[0];
    }
    lst[0][tid] = __float_as_uint(r2[4 + tid]);
    lst[1][tid] = __float_as_uint(r3[4 + tid]);
    __syncthreads();

    const int w = tid >> 6, lane = tid & 63;
    if (w < 2) {
        uint32_t* arr = lst[w];          // positive floats: uint order = float order
        for (int k = 2; k <= 256; k <<= 1) {
            for (int jj = k >> 1; jj > 0; jj >>= 1) {
                for (int i2 = lane; i2 < 256; i2 += 64) {
                    int l = i2 ^ jj;
                    if (l > i2) {
                        uint32_t A = arr[i2], B = arr[l];
                        bool up = ((i2 & k) == 0);
                        if ((A > B) == up) { arr[i2] = B; arr[l] = A; }
                    }
                }
                WSYNC();
            }
        }
        // loss_part = sum of the (256 - prior) smallest entries (zeros pad)
        int pr = prior_sh[w]; if (pr > 256) pr = 256;
        int keep = 256 - pr;
        float s = 0.0f;
        for (int i2 = lane; i2 < 256; i2 += 64)
            if (i2 < keep) s += __uint_as_float(arr[i2]);
        #pragma unroll
        for (int o = 32; o > 0; o >>= 1) s += __shfl_xor(s, o, 64);
        if (lane == 0) csum[w] = s;
    }
    __syncthreads();

    if (tid == 0) {
        float loss = csum[0] + csum[1];
        __hip_atomic_store(&chunkloss[q], loss, __ATOMIC_RELAXED, __HIP_MEMORY_SCOPE_AGENT);
        int old = __hip_atomic_fetch_add(&wsi[8], 1, __ATOMIC_ACQ_REL, __HIP_MEMORY_SCOPE_AGENT);
        if (old == 7) {
            float tt = 0.0f;
            for (int i = 0; i < 8; ++i)
                tt += __hip_atomic_load(&chunkloss[i], __ATOMIC_RELAXED, __HIP_MEMORY_SCOPE_AGENT);
            out[0] = tt * 0.125f;
        }
    }
}

extern "C" void kernel_launch(void* const* d_in, const int* in_sizes, int n_in,
                              void* d_out, int out_size, void* d_ws, size_t ws_size,
                              hipStream_t stream) {
    const float* x = (const float*)d_in[0];
    const float* y = (const float*)d_in[1];
    const int* offs = (const int*)d_in[2];
    hipMemsetAsync(d_ws, 0, 64, stream);    // zero the finalize counter
    pd_kernel<<<32, 256, 0, stream>>>(x, y, offs, (float*)d_ws);
    loss_kernel<<<8, 256, 0, stream>>>((float*)d_ws, (float*)d_out);
}

// Round 12
// 112.767 us; speedup vs baseline: 2.3453x; 1.0912x over previous
//
#include <hip/hip_runtime.h>
#include <stdint.h>

typedef unsigned long long u64;
#define INFK 0xFFFFFFFFu
#define EMPTY 0xFFFFFFFFu
#define HSZ 2048
#define DREG 264   // floats per diagram region: [0]=npos, [4..259]=poslist

// In-wave phase sync (wave-local LDS ordering; no block barrier)
#define WSYNC() asm volatile("s_waitcnt lgkmcnt(0)" ::: "memory")

__device__ __forceinline__ uint32_t f2s(float f) {
    uint32_t u = __float_as_uint(f);
    return (u & 0x80000000u) ? ~u : (u | 0x80000000u);
}
__device__ __forceinline__ float s2f(uint32_t s) {
    uint32_t u = (s & 0x80000000u) ? (s & 0x7fffffffu) : ~s;
    return __uint_as_float(u);
}

// Lock-free triplet merge-tree insertion (validated rounds 3/4/10/11).
// The two root walks are INTERLEAVED: independent LDS chains, both reads
// in flight per iteration -> half the dependent-latency critical path.
__device__ __forceinline__ void tmerge(u64* trip, const u64* bku,
                                       int a, int b, uint32_t w) {
    while (true) {
        int ra = a, rb = b;
        while (true) {
            u64 ta = *(volatile u64*)&trip[ra];
            u64 tb = *(volatile u64*)&trip[rb];
            bool ma = ((uint32_t)(ta >> 32)) <= w;
            bool mb = ((uint32_t)(tb >> 32)) <= w;
            if (!ma && !mb) break;
            if (ma) ra = (int)(ta & 0xFFFFu);
            if (mb) rb = (int)(tb & 0xFFFFu);
        }
        if (ra == rb) return;
        int y, e;
        if (bku[ra] < bku[rb]) { e = ra; y = rb; } else { e = rb; y = ra; }
        u64 old = *(volatile u64*)&trip[y];
        uint32_t sy = (uint32_t)(old >> 32);
        if (sy <= w) continue;                 // concurrent change; re-walk
        u64 nw = ((u64)w << 32) | (unsigned)e;
        if (atomicCAS(&trip[y], old, nw) == old) {
            if (sy == INFK) return;            // no displaced fact
            a = y; b = (int)(old & 0xFFFFu); w = sy;   // re-insert displaced fact
        }
    }
}

// One block per diagram (bid = chunk*4 + c; c: 0=-y,1=+y,2=-x,3=+x).
// Basins (descent + 4-way-interleaved register chase) -> pair-dedup hash
// (min weight per basin pair) -> lock-free tmerge on unique pairs only.
__global__ __launch_bounds__(256) void pd_kernel(
        const float* __restrict__ xin, const float* __restrict__ yin,
        const int* __restrict__ offs, float* __restrict__ ws)
{
    __shared__ uint32_t key[1024];
    __shared__ unsigned short sd[1024];
    __shared__ unsigned short rnk[1024];
    __shared__ u64 bku[384];       // rank -> birth key (key<<10 | vertex)
    __shared__ u64 trip[384];      // rank -> (death<<32 | elder_rank)
    __shared__ uint32_t hpair[HSZ], hwt[HSZ];
    __shared__ uint32_t poslist[256];
    __shared__ int cnt, nslot;

    const int bid = blockIdx.x;
    const int q = bid >> 2, c = bid & 3, b = q >> 1;
    const int tid = threadIdx.x;
    const int off0 = offs[q * 2], off1 = offs[q * 2 + 1];
    const float* img = (c >> 1) ? (xin + b * 160000) : (yin + b * 160000);
    const bool neg = ((c & 1) == 0);

    if (bid == 0 && tid == 0) ((int*)ws)[8] = 0;   // finalize counter (no memset)
    if (tid == 0) { cnt = 0; nslot = 0; }
    poslist[tid] = 0u;
    for (int s = tid; s < HSZ; s += 256) { hpair[s] = EMPTY; hwt[s] = EMPTY; }

    // ---- load chunk with +1.0 contour border; f2s(-v) == ~f2s(v) ----
    uint32_t kreg[4];
    for (int s = 0; s < 4; ++s) {
        int u = tid + 256 * s;
        int i = u >> 5, j = u & 31;
        bool border = (i == 0) | (i == 31) | (j == 0) | (j == 31);
        float val = border ? 1.0f : img[(off0 + i - 1) * 400 + (off1 + j - 1)];
        uint32_t k = f2s(val);
        k = neg ? ~k : k;
        kreg[s] = k;
        key[u] = k;
    }
    __syncthreads();

    // ---- steepest descent (strict total order (key,idx)) ----
    const int DI[6] = {-1, 1, 0, 0, 1, -1};
    const int DJ[6] = { 0, 0,-1, 1, 1, -1};
    for (int s = 0; s < 4; ++s) {
        int u = tid + 256 * s;
        int i = u >> 5, j = u & 31;
        u64 bestk = ((u64)kreg[s] << 10) | (unsigned)u;
        int bi = u;
        #pragma unroll
        for (int d = 0; d < 6; ++d) {
            int ni = i + DI[d], nj = j + DJ[d];
            if (ni < 0 || ni > 31 || nj < 0 || nj > 31) continue;
            int nb2 = (ni << 5) | nj;
            u64 kn = ((u64)key[nb2] << 10) | (unsigned)nb2;
            if (kn < bestk) { bestk = kn; bi = nb2; }
        }
        sd[u] = (unsigned short)bi;
    }
    __syncthreads();

    // ---- 4-way interleaved register chase to basin min ----
    {
        const int u0 = tid, u1 = tid + 256, u2 = tid + 512, u3 = tid + 768;
        int r0 = sd[u0], r1 = sd[u1], r2 = sd[u2], r3 = sd[u3];
        while (true) {
            int p0 = sd[r0], p1 = sd[r1], p2 = sd[r2], p3 = sd[r3];
            if (p0 == r0 && p1 == r1 && p2 == r2 && p3 == r3) break;
            r0 = p0; r1 = p1; r2 = p2; r3 = p3;
        }
        sd[u0] = (unsigned short)r0;   // monotone shortcut writes (benign races)
        sd[u1] = (unsigned short)r1;
        sd[u2] = (unsigned short)r2;
        sd[u3] = (unsigned short)r3;
    }
    __syncthreads();

    // ---- dense-rank minima; init triplets ----
    for (int s = 0; s < 4; ++s) {
        int u = tid + 256 * s;
        if (sd[u] == (unsigned short)u) {
            int r = atomicAdd(&cnt, 1);
            if (r < 384) {
                rnk[u] = (unsigned short)r;
                bku[r] = ((u64)kreg[s] << 10) | (unsigned)u;
                trip[r] = ((u64)INFK << 32) | (unsigned)r;
            }
        }
    }
    __syncthreads();

    // ---- pair-dedup: hash (CAS claim + atomicMin weight), round-5 validated ----
    const int CDI[3] = {1, 0, 1}, CDJ[3] = {0, 1, 1};
    for (int s = 0; s < 4; ++s) {
        int u = tid + 256 * s;
        int i = u >> 5, j = u & 31;
        uint32_t ku = kreg[s];
        int sa = sd[u];
        #pragma unroll
        for (int d = 0; d < 3; ++d) {
            int ni = i + CDI[d], nj = j + CDJ[d];
            if (ni > 31 || nj > 31) continue;
            int nb2 = (ni << 5) | nj;
            int sb = sd[nb2];
            if (sa == sb) continue;
            uint32_t kn = key[nb2];
            uint32_t w = ku > kn ? ku : kn;
            int a = rnk[sa], b2 = rnk[sb];
            if (a > b2) { int t = a; a = b2; b2 = t; }
            uint32_t pk = ((uint32_t)a << 9) | (uint32_t)b2;
            uint32_t h = (pk * 2654435761u) >> 21;
            while (true) {
                uint32_t old = atomicCAS(&hpair[h], EMPTY, pk);
                if (old == EMPTY || old == pk) { atomicMin(&hwt[h], w); break; }
                h = (h + 1) & (HSZ - 1);
            }
        }
    }
    __syncthreads();

    // ---- lock-free triplet merges over UNIQUE pairs (straight off hash) ----
    for (int s = tid; s < HSZ; s += 256) {
        uint32_t pk = hpair[s];
        if (pk != EMPTY)
            tmerge(trip, bku, (int)(pk >> 9), (int)(pk & 511u), hwt[s]);
    }
    __syncthreads();

    // ---- collect positive bar lengths ----
    for (int t = tid; t < 384; t += 256) {
        if (t < cnt) {
            u64 tt = trip[t];
            uint32_t sv = (uint32_t)(tt >> 32);
            if (sv != INFK) {
                float len = s2f(sv) - s2f((uint32_t)(bku[t] >> 10));
                if (len > 0.0f) {
                    int sl = atomicAdd(&nslot, 1);
                    if (sl < 256) poslist[sl] = __float_as_uint(len);
                }
            }
        }
    }
    __syncthreads();

    // ---- publish (plain stores; loss_kernel is stream-ordered after us) ----
    float* reg = ws + 32 + bid * DREG;
    reg[4 + tid] = __uint_as_float(poslist[tid]);
    if (tid == 0) reg[0] = (float)nslot;
}

// One block per chunk: combine 4 diagrams -> chunk loss; last block -> mean.
__global__ __launch_bounds__(256) void loss_kernel(float* __restrict__ ws,
                                                   float* __restrict__ out)
{
    __shared__ uint32_t lst[2][256];
    __shared__ float csum[2];
    __shared__ int prior_sh[2];

    const int q = blockIdx.x, tid = threadIdx.x;
    int* wsi = (int*)ws;
    float* chunkloss = ws + 16;
    const float* r0 = ws + 32 + (q * 4 + 0) * DREG;
    const float* r1 = ws + 32 + (q * 4 + 1) * DREG;
    const float* r2 = ws + 32 + (q * 4 + 2) * DREG;
    const float* r3 = ws + 32 + (q * 4 + 3) * DREG;

    if (tid == 0) {
        prior_sh[0] = (int)r0[0] + 1;   // +1: infinite essential dim-0 bar
        prior_sh[1] = (int)r1[0];
    }
    lst[0][tid] = __float_as_uint(r2[4 + tid]);
    lst[1][tid] = __float_as_uint(r3[4 + tid]);
    __syncthreads();

    const int w = tid >> 6, lane = tid & 63;
    if (w < 2) {
        uint32_t* arr = lst[w];          // positive floats: uint order = float order
        for (int k = 2; k <= 256; k <<= 1) {
            for (int jj = k >> 1; jj > 0; jj >>= 1) {
                for (int i2 = lane; i2 < 256; i2 += 64) {
                    int l = i2 ^ jj;
                    if (l > i2) {
                        uint32_t A = arr[i2], B = arr[l];
                        bool up = ((i2 & k) == 0);
                        if ((A > B) == up) { arr[i2] = B; arr[l] = A; }
                    }
                }
                WSYNC();
            }
        }
        // loss_part = sum of the (256 - prior) smallest entries (zeros pad)
        int pr = prior_sh[w]; if (pr > 256) pr = 256;
        int keep = 256 - pr;
        float s = 0.0f;
        for (int i2 = lane; i2 < 256; i2 += 64)
            if (i2 < keep) s += __uint_as_float(arr[i2]);
        #pragma unroll
        for (int o = 32; o > 0; o >>= 1) s += __shfl_xor(s, o, 64);
        if (lane == 0) csum[w] = s;
    }
    __syncthreads();

    if (tid == 0) {
        float loss = csum[0] + csum[1];
        __hip_atomic_store(&chunkloss[q], loss, __ATOMIC_RELAXED, __HIP_MEMORY_SCOPE_AGENT);
        int old = __hip_atomic_fetch_add(&wsi[8], 1, __ATOMIC_ACQ_REL, __HIP_MEMORY_SCOPE_AGENT);
        if (old == 7) {
            float tt = 0.0f;
            for (int i = 0; i < 8; ++i)
                tt += __hip_atomic_load(&chunkloss[i], __ATOMIC_RELAXED, __HIP_MEMORY_SCOPE_AGENT);
            out[0] = tt * 0.125f;
        }
    }
}

extern "C" void kernel_launch(void* const* d_in, const int* in_sizes, int n_in,
                              void* d_out, int out_size, void* d_ws, size_t ws_size,
                              hipStream_t stream) {
    const float* x = (const float*)d_in[0];
    const float* y = (const float*)d_in[1];
    const int* offs = (const int*)d_in[2];
    pd_kernel<<<32, 256, 0, stream>>>(x, y, offs, (float*)d_ws);
    loss_kernel<<<8, 256, 0, stream>>>((float*)d_ws, (float*)d_out);
}

// Round 13
// 94.614 us; speedup vs baseline: 2.7952x; 1.1919x over previous
//
#include <hip/hip_runtime.h>
#include <stdint.h>

typedef unsigned long long u64;
#define INFK 0xFFFFFFFFu
#define EMPTY 0xFFFFFFFFu
#define HSZ 2048
#define DREG 264   // floats per diagram region: [0]=npos, [4..259]=poslist

// In-wave phase sync (wave-local LDS ordering; no block barrier)
#define WSYNC() asm volatile("s_waitcnt lgkmcnt(0)" ::: "memory")

__device__ __forceinline__ uint32_t f2s(float f) {
    uint32_t u = __float_as_uint(f);
    return (u & 0x80000000u) ? ~u : (u | 0x80000000u);
}
__device__ __forceinline__ float s2f(uint32_t s) {
    uint32_t u = (s & 0x80000000u) ? (s & 0x7fffffffu) : ~s;
    return __uint_as_float(u);
}

// Lock-free triplet merge-tree insertion (validated rounds 3/4/10/11/12).
// Interleaved root walks: both dependent LDS chains in flight.
__device__ __forceinline__ void tmerge(u64* trip, const u64* bku,
                                       int a, int b, uint32_t w) {
    while (true) {
        int ra = a, rb = b;
        while (true) {
            u64 ta = *(volatile u64*)&trip[ra];
            u64 tb = *(volatile u64*)&trip[rb];
            bool ma = ((uint32_t)(ta >> 32)) <= w;
            bool mb = ((uint32_t)(tb >> 32)) <= w;
            if (!ma && !mb) break;
            if (ma) ra = (int)(ta & 0xFFFFu);
            if (mb) rb = (int)(tb & 0xFFFFu);
        }
        if (ra == rb) return;
        int y, e;
        if (bku[ra] < bku[rb]) { e = ra; y = rb; } else { e = rb; y = ra; }
        u64 old = *(volatile u64*)&trip[y];
        uint32_t sy = (uint32_t)(old >> 32);
        if (sy <= w) continue;                 // concurrent change; re-walk
        u64 nw = ((u64)w << 32) | (unsigned)e;
        if (atomicCAS(&trip[y], old, nw) == old) {
            if (sy == INFK) return;            // no displaced fact
            a = y; b = (int)(old & 0xFFFFu); w = sy;   // re-insert displaced fact
        }
    }
}

// One block per diagram, 1024 threads (16 waves/CU for TLP latency hiding).
// bid = chunk*4 + c; c: 0=-y,1=+y,2=-x,3=+x. One vertex per thread.
// Combine: last block of each chunk-quad (round-10-validated atomics).
__global__ __launch_bounds__(1024) void toploss_k(
        const float* __restrict__ xin, const float* __restrict__ yin,
        const int* __restrict__ offs, float* __restrict__ ws,
        float* __restrict__ out)
{
    __shared__ uint32_t key[1024];
    __shared__ unsigned short sd[1024];
    __shared__ unsigned short rnk[1024];
    __shared__ u64 bku[384];       // rank -> birth key (key<<10 | vertex)
    __shared__ u64 trip[384];      // rank -> (death<<32 | elder_rank)
    __shared__ uint32_t hpair[HSZ], hwt[HSZ];
    __shared__ uint32_t poslist[256];
    __shared__ uint32_t lst[2][256];
    __shared__ float csum[2];
    __shared__ int prior_sh[2];
    __shared__ int cnt, nslot, win;

    const int bid = blockIdx.x;
    const int q = bid >> 2, c = bid & 3, b = q >> 1;
    const int tid = threadIdx.x;
    const int off0 = offs[q * 2], off1 = offs[q * 2 + 1];
    const float* img = (c >> 1) ? (xin + b * 160000) : (yin + b * 160000);
    const bool neg = ((c & 1) == 0);
    int* wsi = (int*)ws;
    float* chunkloss = ws + 16;

    if (tid == 0) { cnt = 0; nslot = 0; }
    if (tid < 256) poslist[tid] = 0u;
    for (int s = tid; s < HSZ; s += 1024) { hpair[s] = EMPTY; hwt[s] = EMPTY; }

    // ---- load chunk with +1.0 contour border; f2s(-v) == ~f2s(v) ----
    const int i = tid >> 5, j = tid & 31;
    uint32_t kreg;
    {
        bool border = (i == 0) | (i == 31) | (j == 0) | (j == 31);
        float val = border ? 1.0f : img[(off0 + i - 1) * 400 + (off1 + j - 1)];
        uint32_t k = f2s(val);
        kreg = neg ? ~k : k;
        key[tid] = kreg;
    }
    __syncthreads();

    // ---- steepest descent (strict total order (key,idx)) ----
    const int DI[6] = {-1, 1, 0, 0, 1, -1};
    const int DJ[6] = { 0, 0,-1, 1, 1, -1};
    {
        u64 bestk = ((u64)kreg << 10) | (unsigned)tid;
        int bi = tid;
        #pragma unroll
        for (int d = 0; d < 6; ++d) {
            int ni = i + DI[d], nj = j + DJ[d];
            if (ni < 0 || ni > 31 || nj < 0 || nj > 31) continue;
            int nb2 = (ni << 5) | nj;
            u64 kn = ((u64)key[nb2] << 10) | (unsigned)nb2;
            if (kn < bestk) { bestk = kn; bi = nb2; }
        }
        sd[tid] = (unsigned short)bi;
    }
    __syncthreads();

    // ---- register chase to basin min (TLP across 16 waves hides latency) ----
    {
        int r = sd[tid];
        int p = sd[r];
        while (p != r) { r = p; p = sd[r]; }
        sd[tid] = (unsigned short)r;   // monotone shortcut write (benign race)
    }
    __syncthreads();

    // ---- dense-rank minima; init triplets ----
    if (sd[tid] == (unsigned short)tid) {
        int r = atomicAdd(&cnt, 1);
        if (r < 384) {
            rnk[tid] = (unsigned short)r;
            bku[r] = ((u64)kreg << 10) | (unsigned)tid;
            trip[r] = ((u64)INFK << 32) | (unsigned)r;
        }
    }
    __syncthreads();

    // ---- pair-dedup hash (CAS claim + atomicMin weight), round-5/12 validated ----
    const int CDI[3] = {1, 0, 1}, CDJ[3] = {0, 1, 1};
    {
        int sa = sd[tid];
        #pragma unroll
        for (int d = 0; d < 3; ++d) {
            int ni = i + CDI[d], nj = j + CDJ[d];
            if (ni > 31 || nj > 31) continue;
            int nb2 = (ni << 5) | nj;
            int sb = sd[nb2];
            if (sa == sb) continue;
            uint32_t kn = key[nb2];
            uint32_t w = kreg > kn ? kreg : kn;
            int a = rnk[sa], b2 = rnk[sb];
            if (a > b2) { int t = a; a = b2; b2 = t; }
            uint32_t pk = ((uint32_t)a << 9) | (uint32_t)b2;
            uint32_t h = (pk * 2654435761u) >> 21;
            while (true) {
                uint32_t old = atomicCAS(&hpair[h], EMPTY, pk);
                if (old == EMPTY || old == pk) { atomicMin(&hwt[h], w); break; }
                h = (h + 1) & (HSZ - 1);
            }
        }
    }
    __syncthreads();

    // ---- lock-free triplet merges over UNIQUE pairs (straight off hash) ----
    for (int s = tid; s < HSZ; s += 1024) {
        uint32_t pk = hpair[s];
        if (pk != EMPTY)
            tmerge(trip, bku, (int)(pk >> 9), (int)(pk & 511u), hwt[s]);
    }
    __syncthreads();

    // ---- collect positive bar lengths ----
    if (tid < 384 && tid < cnt) {
        u64 tt = trip[tid];
        uint32_t sv = (uint32_t)(tt >> 32);
        if (sv != INFK) {
            float len = s2f(sv) - s2f((uint32_t)(bku[tid] >> 10));
            if (len > 0.0f) {
                int sl = atomicAdd(&nslot, 1);
                if (sl < 256) poslist[sl] = __float_as_uint(len);
            }
        }
    }
    __syncthreads();

    // ---- publish diagram results (device-scope atomics) ----
    float* reg = ws + 32 + bid * DREG;
    if (tid < 256)
        __hip_atomic_store(&reg[4 + tid], __uint_as_float(poslist[tid]),
                           __ATOMIC_RELAXED, __HIP_MEMORY_SCOPE_AGENT);
    if (tid == 0)
        __hip_atomic_store(&reg[0], (float)nslot, __ATOMIC_RELAXED, __HIP_MEMORY_SCOPE_AGENT);
    __syncthreads();
    if (tid == 0) {
        int old = __hip_atomic_fetch_add(&wsi[q], 1, __ATOMIC_ACQ_REL, __HIP_MEMORY_SCOPE_AGENT);
        win = (old == 3);
    }
    __syncthreads();

    // ---- last block of the chunk-quad combines ----
    if (win) {
        const float* r0 = ws + 32 + (q * 4 + 0) * DREG;
        const float* r1 = ws + 32 + (q * 4 + 1) * DREG;
        const float* r2 = ws + 32 + (q * 4 + 2) * DREG;
        const float* r3 = ws + 32 + (q * 4 + 3) * DREG;
        if (tid == 0) {
            prior_sh[0] = (int)__hip_atomic_load(&r0[0], __ATOMIC_RELAXED, __HIP_MEMORY_SCOPE_AGENT) + 1;
            prior_sh[1] = (int)__hip_atomic_load(&r1[0], __ATOMIC_RELAXED, __HIP_MEMORY_SCOPE_AGENT);
        }
        if (tid < 256) {
            lst[0][tid] = __float_as_uint(__hip_atomic_load(&r2[4 + tid], __ATOMIC_RELAXED, __HIP_MEMORY_SCOPE_AGENT));
            lst[1][tid] = __float_as_uint(__hip_atomic_load(&r3[4 + tid], __ATOMIC_RELAXED, __HIP_MEMORY_SCOPE_AGENT));
        }
        __syncthreads();
        const int w = tid >> 6, lane = tid & 63;
        if (w < 2) {
            uint32_t* arr = lst[w];      // positive floats: uint order = float order
            for (int k = 2; k <= 256; k <<= 1) {
                for (int jj = k >> 1; jj > 0; jj >>= 1) {
                    for (int i2 = lane; i2 < 256; i2 += 64) {
                        int l = i2 ^ jj;
                        if (l > i2) {
                            uint32_t A = arr[i2], B = arr[l];
                            bool up = ((i2 & k) == 0);
                            if ((A > B) == up) { arr[i2] = B; arr[l] = A; }
                        }
                    }
                    WSYNC();
                }
            }
            // loss_part = sum of the (256 - prior) smallest entries (zeros pad)
            int pr = prior_sh[w]; if (pr > 256) pr = 256;
            int keep = 256 - pr;
            float s = 0.0f;
            for (int i2 = lane; i2 < 256; i2 += 64)
                if (i2 < keep) s += __uint_as_float(arr[i2]);
            #pragma unroll
            for (int o = 32; o > 0; o >>= 1) s += __shfl_xor(s, o, 64);
            if (lane == 0) csum[w] = s;
        }
        __syncthreads();
        if (tid == 0) {
            float loss = csum[0] + csum[1];
            __hip_atomic_store(&chunkloss[q], loss, __ATOMIC_RELAXED, __HIP_MEMORY_SCOPE_AGENT);
            int old2 = __hip_atomic_fetch_add(&wsi[8], 1, __ATOMIC_ACQ_REL, __HIP_MEMORY_SCOPE_AGENT);
            if (old2 == 7) {
                float tt = 0.0f;
                for (int i2 = 0; i2 < 8; ++i2)
                    tt += __hip_atomic_load(&chunkloss[i2], __ATOMIC_RELAXED, __HIP_MEMORY_SCOPE_AGENT);
                out[0] = tt * 0.125f;
            }
        }
    }
}

extern "C" void kernel_launch(void* const* d_in, const int* in_sizes, int n_in,
                              void* d_out, int out_size, void* d_ws, size_t ws_size,
                              hipStream_t stream) {
    const float* x = (const float*)d_in[0];
    const float* y = (const float*)d_in[1];
    const int* offs = (const int*)d_in[2];
    hipMemsetAsync(d_ws, 0, 64, stream);    // zero quad + finalize counters
    toploss_k<<<32, 1024, 0, stream>>>(x, y, offs, (float*)d_ws, (float*)d_out);
}